// Round 4
// baseline (54.281 us; speedup 1.0000x reference)
//
#include <hip/hip_runtime.h>
#include <hip/hip_bf16.h>

// Problem constants: B=8, T=128, n=127 neighbors, Q=K=64, H=4, O=H*K=256
#define NB 127

typedef __attribute__((ext_vector_type(8))) short bf16x8;
typedef __attribute__((ext_vector_type(4))) float f32x4;

// ws layout: packed bf16 MFMA fragments (A/B-frag lane layout is identical), 4 x 32KB.
// short-offsets:
#define WKP_S  0
#define WVP_S  16384
#define WQP_S  32768
#define WVQP_S 49152
#define WS_NEEDED ((size_t)(4 * 16384 * 2))

__device__ __forceinline__ short bfs(float f) {
  __hip_bfloat16 h = __float2bfloat16(f);
  return __builtin_bit_cast(short, h);
}
__device__ __forceinline__ unsigned packbf2(float a, float b) {
  unsigned lo = (unsigned short)bfs(a);
  unsigned hi = (unsigned short)bfs(b);
  return lo | (hi << 16);
}
// gather 8 consecutive floats -> bf16x8 fragment
__device__ __forceinline__ bf16x8 gath(const float* __restrict__ p) {
  float4 a = *(const float4*)p;
  float4 b = *(const float4*)(p + 4);
  bf16x8 f;
  f[0] = bfs(a.x); f[1] = bfs(a.y); f[2] = bfs(a.z); f[3] = bfs(a.w);
  f[4] = bfs(b.x); f[5] = bfs(b.y); f[6] = bfs(b.z); f[7] = bfs(b.w);
  return f;
}

// ================= pack kernel (grid 32): coalesced f32 reads -> fragment-order bf16 ====
// frag layout: lane (= g*16 + l15) of fragment (head,nt,kt) holds
//   W[o = head*64 + nt*16 + l15][k = g*8 + kt*32 + j], j=0..7
__global__ __launch_bounds__(256, 2) void
pack_kernel(const float* __restrict__ Wk, const float* __restrict__ Wq,
            const float* __restrict__ Wv, short* __restrict__ dstall)
{
  const int blk = blockIdx.x;
  const int tid = threadIdx.x;
  const int m = blk >> 3, sub = blk & 7;
  const float* src; int stride, off, dsto;
  if (m == 0)      { src = Wk; stride = 64;  off = 0;  dsto = WKP_S; }
  else if (m == 1) { src = Wv; stride = 128; off = 0;  dsto = WVP_S; }   // Wv kv-part
  else if (m == 2) { src = Wq; stride = 64;  off = 0;  dsto = WQP_S; }
  else             { src = Wv; stride = 128; off = 64; dsto = WVQP_S; }  // Wv q-part
  short* dst = dstall + dsto;
  #pragma unroll
  for (int it = 0; it < 2; ++it) {
    int i4 = sub * 512 + it * 256 + tid;    // float4 index in 256x64 submatrix
    int o = i4 >> 4, c4 = i4 & 15;
    float4 v = ((const float4*)(src + o * stride + off))[c4];
    int k0 = c4 * 4;
    int kt = k0 >> 5, gg = (k0 & 31) >> 3, j0 = k0 & 7;
    int head = o >> 6, nt = (o >> 4) & 3, ol = o & 15;
    int di = ((((head * 4 + nt) * 2 + kt) * 64) + gg * 16 + ol) * 8 + j0;
    *(uint2*)(dst + di) = make_uint2(packbf2(v.x, v.y), packbf2(v.z, v.w));
  }
}

// ================= main kernel (grid 1024, wave = head) =================
// Orientation: mfma(W_frag, kv_frag) -> C[o = g*4+r][n = l15].
// Scores reduce over o (2 shfl/mt); softmax dim n is lane-indexed; PV weights lane-local.
template <int PREP>
__global__ __launch_bounds__(256, 4) void
rnn_attn_kernel(const float* __restrict__ q_x, const float* __restrict__ kv_x,
                const float* __restrict__ Wk, const float* __restrict__ Wq,
                const float* __restrict__ Wv, const float* __restrict__ bv,
                const float* __restrict__ bias, const float* __restrict__ wsc,
                const short* __restrict__ pack, float* __restrict__ out)
{
  __shared__ __align__(16) unsigned char Atile[128 * 128];

  const int tid = threadIdx.x;
  const int bt = blockIdx.x;
  const int lane = tid & 63;
  const int head = tid >> 6;
  const int l15 = lane & 15;
  const int g = lane >> 4;

  // ---- stage kv tile (127x64 f32 -> bf16, XOR-swizzled), coalesced ----
  const float* kv = kv_x + (size_t)bt * (NB * 64);
  #pragma unroll
  for (int i = 0; i < 8; ++i) {
    int idx = i * 256 + tid;
    int row = idx >> 4, c = idx & 15;
    float4 v = (row < NB) ? ((const float4*)kv)[idx] : make_float4(0.f, 0.f, 0.f, 0.f);
    int byte = (row << 7) + (c << 3);
    byte ^= ((row & 7) << 4);
    *(uint2*)(&Atile[byte]) = make_uint2(packbf2(v.x, v.y), packbf2(v.z, v.w));
  }

  // ---- q broadcast fragments: lane holds q[g*8 + kt*32 + j] for all l15 ----
  bf16x8 qf0 = gath(q_x + bt * 64 + g * 8);
  bf16x8 qf1 = gath(q_x + bt * 64 + 32 + g * 8);

  // ---- per-lane o-vector of score weights: ws[o = nt*16 + g*4 + r] ----
  f32x4 ws4[4];
  #pragma unroll
  for (int nt = 0; nt < 4; ++nt) {
    float4 t = ((const float4*)wsc)[nt * 4 + g];
    ws4[nt] = (f32x4){t.x, t.y, t.z, t.w};
  }

  // ---- Wk fragments ----
  bf16x8 bk[4][2];
  if (PREP) {
    const bf16x8* pw = (const bf16x8*)(pack + WKP_S);
    #pragma unroll
    for (int nt = 0; nt < 4; ++nt) {
      bk[nt][0] = pw[((head * 4 + nt) * 2 + 0) * 64 + lane];
      bk[nt][1] = pw[((head * 4 + nt) * 2 + 1) * 64 + lane];
    }
  } else {
    #pragma unroll
    for (int nt = 0; nt < 4; ++nt) {
      int o = head * 64 + nt * 16 + l15;
      bk[nt][0] = gath(Wk + o * 64 + g * 8);
      bk[nt][1] = gath(Wk + o * 64 + 32 + g * 8);
    }
  }

  // ---- qq/qv via broadcast-B MFMA; bias/bv folded in as C-in ----
  // result: qq[nt][r] = q@Wq.T[o] + bias[o&63], o = head*64+nt*16+g*4+r, same in all l15
  f32x4 qq[4], qv[4];
  #pragma unroll
  for (int nt = 0; nt < 4; ++nt) {
    bf16x8 wq0, wq1, wv0, wv1;
    if (PREP) {
      const bf16x8* pw = (const bf16x8*)(pack + WQP_S);
      const bf16x8* pv = (const bf16x8*)(pack + WVQP_S);
      wq0 = pw[((head * 4 + nt) * 2 + 0) * 64 + lane];
      wq1 = pw[((head * 4 + nt) * 2 + 1) * 64 + lane];
      wv0 = pv[((head * 4 + nt) * 2 + 0) * 64 + lane];
      wv1 = pv[((head * 4 + nt) * 2 + 1) * 64 + lane];
    } else {
      int o = head * 64 + nt * 16 + l15;
      wq0 = gath(Wq + o * 64 + g * 8);
      wq1 = gath(Wq + o * 64 + 32 + g * 8);
      wv0 = gath(Wv + o * 128 + 64 + g * 8);
      wv1 = gath(Wv + o * 128 + 64 + 32 + g * 8);
    }
    float4 bs4 = ((const float4*)bias)[nt * 4 + g];
    float4 bv4 = ((const float4*)(bv + head * 64))[nt * 4 + g];
    f32x4 a = (f32x4){bs4.x, bs4.y, bs4.z, bs4.w};
    a = __builtin_amdgcn_mfma_f32_16x16x32_bf16(wq0, qf0, a, 0, 0, 0);
    a = __builtin_amdgcn_mfma_f32_16x16x32_bf16(wq1, qf1, a, 0, 0, 0);
    qq[nt] = a;
    f32x4 b = (f32x4){bv4.x, bv4.y, bv4.z, bv4.w};
    b = __builtin_amdgcn_mfma_f32_16x16x32_bf16(wv0, qf0, b, 0, 0, 0);
    b = __builtin_amdgcn_mfma_f32_16x16x32_bf16(wv1, qf1, b, 0, 0, 0);
    qv[nt] = b;
  }

  __syncthreads();

  // ---- Phase C: keys^T GEMM + tanh-score; score[n=mt*16+l15] in register sr[mt] ----
  float sr[8];
  #pragma unroll
  for (int mt = 0; mt < 8; ++mt) {
    int row = mt * 16 + l15;
    int byte0 = (row << 7) + g * 16;
    int swz = (l15 & 7) << 4;
    bf16x8 a0 = *(const bf16x8*)(&Atile[byte0 ^ swz]);
    bf16x8 a1 = *(const bf16x8*)(&Atile[(byte0 + 64) ^ swz]);
    float p = 0.f;
    #pragma unroll
    for (int nt = 0; nt < 4; ++nt) {
      f32x4 acc = qq[nt];    // C-in = queries + bias (broadcast over cols)
      acc = __builtin_amdgcn_mfma_f32_16x16x32_bf16(bk[nt][0], a0, acc, 0, 0, 0);
      acc = __builtin_amdgcn_mfma_f32_16x16x32_bf16(bk[nt][1], a1, acc, 0, 0, 0);
      #pragma unroll
      for (int r = 0; r < 4; ++r) {
        float e = __expf(2.f * acc[r]);                 // tanh(x) = 1 - 2/(e^(2x)+1)
        float th = 1.f - 2.f * __builtin_amdgcn_rcpf(e + 1.f);
        p = fmaf(ws4[nt][r], th, p);
      }
    }
    p += __shfl_xor(p, 16);    // reduce over o across g-groups
    p += __shfl_xor(p, 32);
    sr[mt] = p;                // full score, identical in all g
  }

  // ---- load Wv_kv fragments (hide under softmax) ----
  bf16x8 bw[4][2];
  if (PREP) {
    const bf16x8* pw = (const bf16x8*)(pack + WVP_S);
    #pragma unroll
    for (int nt = 0; nt < 4; ++nt) {
      bw[nt][0] = pw[((head * 4 + nt) * 2 + 0) * 64 + lane];
      bw[nt][1] = pw[((head * 4 + nt) * 2 + 1) * 64 + lane];
    }
  } else {
    #pragma unroll
    for (int nt = 0; nt < 4; ++nt) {
      int o = head * 64 + nt * 16 + l15;
      bw[nt][0] = gath(Wv + o * 128 + g * 8);
      bw[nt][1] = gath(Wv + o * 128 + 32 + g * 8);
    }
  }

  // ---- Phase D: softmax over n=127 (regs + 8 shfl total) ----
  if (l15 == 15) sr[7] = -3.0e38f;        // mask pad row n=127
  float m = fmaxf(fmaxf(fmaxf(sr[0], sr[1]), fmaxf(sr[2], sr[3])),
                  fmaxf(fmaxf(sr[4], sr[5]), fmaxf(sr[6], sr[7])));
  #pragma unroll
  for (int d = 1; d < 16; d <<= 1) m = fmaxf(m, __shfl_xor(m, d));
  float sum = 0.f;
  #pragma unroll
  for (int mt = 0; mt < 8; ++mt) { sr[mt] = __expf(sr[mt] - m); sum += sr[mt]; }
  #pragma unroll
  for (int d = 1; d < 16; d <<= 1) sum += __shfl_xor(sum, d);
  float inv = __builtin_amdgcn_rcpf(sum);
  #pragma unroll
  for (int mt = 0; mt < 8; ++mt) sr[mt] *= inv;   // sr[mt] = softmax weight for n=mt*16+l15

  // ---- Phase E: V^T GEMM + weighted accumulate (weights lane-local, zero shfl) ----
  f32x4 cs[4];
  #pragma unroll
  for (int nt = 0; nt < 4; ++nt) cs[nt] = (f32x4){0.f, 0.f, 0.f, 0.f};
  #pragma unroll
  for (int mt = 0; mt < 8; ++mt) {
    int row = mt * 16 + l15;
    int byte0 = (row << 7) + g * 16;
    int swz = (l15 & 7) << 4;
    bf16x8 a0 = *(const bf16x8*)(&Atile[byte0 ^ swz]);
    bf16x8 a1 = *(const bf16x8*)(&Atile[(byte0 + 64) ^ swz]);
    float wgt = sr[mt];
    #pragma unroll
    for (int nt = 0; nt < 4; ++nt) {
      f32x4 vac = (f32x4){0.f, 0.f, 0.f, 0.f};
      vac = __builtin_amdgcn_mfma_f32_16x16x32_bf16(bw[nt][0], a0, vac, 0, 0, 0);
      vac = __builtin_amdgcn_mfma_f32_16x16x32_bf16(bw[nt][1], a1, vac, 0, 0, 0);
      #pragma unroll
      for (int r = 0; r < 4; ++r) cs[nt][r] = fmaf(vac[r], wgt, cs[nt][r]);
    }
  }

  // ---- final reduce over l15 and store ----
  #pragma unroll
  for (int nt = 0; nt < 4; ++nt) {
    #pragma unroll
    for (int d = 1; d < 16; d <<= 1) {
      #pragma unroll
      for (int r = 0; r < 4; ++r) cs[nt][r] += __shfl_xor(cs[nt][r], d);
    }
  }
  if (l15 == 0) {
    #pragma unroll
    for (int nt = 0; nt < 4; ++nt) {
      float4 o4 = make_float4(cs[nt][0] + qv[nt][0], cs[nt][1] + qv[nt][1],
                              cs[nt][2] + qv[nt][2], cs[nt][3] + qv[nt][3]);
      ((float4*)out)[bt * 64 + head * 16 + nt * 4 + g] = o4;
    }
  }
}

extern "C" void kernel_launch(void* const* d_in, const int* in_sizes, int n_in,
                              void* d_out, int out_size, void* d_ws, size_t ws_size,
                              hipStream_t stream) {
  const float* q_x  = (const float*)d_in[0];
  const float* kv_x = (const float*)d_in[1];
  const float* Wk   = (const float*)d_in[2];
  const float* Wq   = (const float*)d_in[3];
  const float* Wv   = (const float*)d_in[4];
  const float* bv   = (const float*)d_in[5];
  const float* bias = (const float*)d_in[6];
  const float* wsc  = (const float*)d_in[7];
  // d_in[8] = bs: constant across neighbors -> cancels in softmax, unused.
  float* out = (float*)d_out;
  short* pack = (short*)d_ws;

  if (ws_size >= WS_NEEDED) {
    pack_kernel<<<32, 256, 0, stream>>>(Wk, Wq, Wv, pack);
    rnn_attn_kernel<1><<<1024, 256, 0, stream>>>(q_x, kv_x, Wk, Wq, Wv, bv, bias, wsc, pack, out);
  } else {
    rnn_attn_kernel<0><<<1024, 256, 0, stream>>>(q_x, kv_x, Wk, Wq, Wv, bv, bias, wsc, pack, out);
  }
}

// Round 5
// 50.161 us; speedup vs baseline: 1.0821x; 1.0821x over previous
//
#include <hip/hip_runtime.h>
#include <hip/hip_bf16.h>

// Problem constants: B=8, T=128, n=127 neighbors, Q=K=64, H=4, O=H*K=256
#define NB 127

typedef __attribute__((ext_vector_type(8))) short bf16x8;
typedef __attribute__((ext_vector_type(4))) float f32x4;

// ws layout: packed bf16 MFMA fragments (A/B-frag lane layout is identical), 4 x 32KB.
// short-offsets:
#define WKP_S  0
#define WVP_S  16384
#define WQP_S  32768
#define WVQP_S 49152
#define WS_NEEDED ((size_t)(4 * 16384 * 2))

__device__ __forceinline__ short bfs(float f) {
  __hip_bfloat16 h = __float2bfloat16(f);
  return __builtin_bit_cast(short, h);
}
__device__ __forceinline__ unsigned packbf2(float a, float b) {
  unsigned lo = (unsigned short)bfs(a);
  unsigned hi = (unsigned short)bfs(b);
  return lo | (hi << 16);
}
// gather 8 consecutive floats -> bf16x8 fragment
__device__ __forceinline__ bf16x8 gath(const float* __restrict__ p) {
  float4 a = *(const float4*)p;
  float4 b = *(const float4*)(p + 4);
  bf16x8 f;
  f[0] = bfs(a.x); f[1] = bfs(a.y); f[2] = bfs(a.z); f[3] = bfs(a.w);
  f[4] = bfs(b.x); f[5] = bfs(b.y); f[6] = bfs(b.z); f[7] = bfs(b.w);
  return f;
}

// ================= pack kernel (grid 32): coalesced f32 reads -> fragment-order bf16 ====
// frag layout: lane (= g*16 + l15) of fragment (head,nt,kt) holds
//   W[o = head*64 + nt*16 + l15][k = g*8 + kt*32 + j], j=0..7
__global__ __launch_bounds__(256, 2) void
pack_kernel(const float* __restrict__ Wk, const float* __restrict__ Wq,
            const float* __restrict__ Wv, short* __restrict__ dstall)
{
  const int blk = blockIdx.x;
  const int tid = threadIdx.x;
  const int m = blk >> 3, sub = blk & 7;
  const float* src; int stride, off, dsto;
  if (m == 0)      { src = Wk; stride = 64;  off = 0;  dsto = WKP_S; }
  else if (m == 1) { src = Wv; stride = 128; off = 0;  dsto = WVP_S; }   // Wv kv-part
  else if (m == 2) { src = Wq; stride = 64;  off = 0;  dsto = WQP_S; }
  else             { src = Wv; stride = 128; off = 64; dsto = WVQP_S; }  // Wv q-part
  short* dst = dstall + dsto;
  #pragma unroll
  for (int it = 0; it < 2; ++it) {
    int i4 = sub * 512 + it * 256 + tid;    // float4 index in 256x64 submatrix
    int o = i4 >> 4, c4 = i4 & 15;
    float4 v = ((const float4*)(src + o * stride + off))[c4];
    int k0 = c4 * 4;
    int kt = k0 >> 5, gg = (k0 & 31) >> 3, j0 = k0 & 7;
    int head = o >> 6, nt = (o >> 4) & 3, ol = o & 15;
    int di = ((((head * 4 + nt) * 2 + kt) * 64) + gg * 16 + ol) * 8 + j0;
    *(uint2*)(dst + di) = make_uint2(packbf2(v.x, v.y), packbf2(v.z, v.w));
  }
}

// ================= main kernel (grid 1024, wave = head) =================
// Orientation: mfma(W_frag, kv_frag) -> C[o = g*4+r][n = l15].
// Register discipline (fit 128-VGPR cap, no spills):
//   prologue: wq/wv frags die after qq/qv MFMAs; qv stashed to LDS (frees 16);
//   Phase C: only bk+qq+ws4+sr live;  Phase E: only bw+cs+sr live (bw loaded
//   AFTER softmax so bk/bw never coexist).
template <int PREP>
__global__ __launch_bounds__(256, 4) void
rnn_attn_kernel(const float* __restrict__ q_x, const float* __restrict__ kv_x,
                const float* __restrict__ Wk, const float* __restrict__ Wq,
                const float* __restrict__ Wv, const float* __restrict__ bv,
                const float* __restrict__ bias, const float* __restrict__ wsc,
                const short* __restrict__ pack, float* __restrict__ out)
{
  __shared__ __align__(16) unsigned char Atile[128 * 128];
  __shared__ float4 qv_lds[4][4][4];   // [head][nt][g]

  const int tid = threadIdx.x;
  const int bt = blockIdx.x;
  const int lane = tid & 63;
  const int head = tid >> 6;
  const int l15 = lane & 15;
  const int g = lane >> 4;

  // ---- stage kv tile (127x64 f32 -> bf16, XOR-swizzled), coalesced ----
  const float* kv = kv_x + (size_t)bt * (NB * 64);
  #pragma unroll
  for (int i = 0; i < 8; ++i) {
    int idx = i * 256 + tid;
    int row = idx >> 4, c = idx & 15;
    float4 v = (row < NB) ? ((const float4*)kv)[idx] : make_float4(0.f, 0.f, 0.f, 0.f);
    int byte = (row << 7) + (c << 3);
    byte ^= ((row & 7) << 4);
    *(uint2*)(&Atile[byte]) = make_uint2(packbf2(v.x, v.y), packbf2(v.z, v.w));
  }

  // ---- qq/qv via broadcast-B MFMA; bias/bv folded in as C-in ----
  // qq[nt][r] = q@Wq.T[o] + bias[o&63], o = head*64+nt*16+g*4+r (same in all l15)
  {
    bf16x8 qf0 = gath(q_x + bt * 64 + g * 8);
    bf16x8 qf1 = gath(q_x + bt * 64 + 32 + g * 8);
    #pragma unroll
    for (int nt = 0; nt < 4; ++nt) {
      bf16x8 wq0, wq1, wv0, wv1;
      if (PREP) {
        const bf16x8* pw = (const bf16x8*)(pack + WQP_S);
        const bf16x8* pv = (const bf16x8*)(pack + WVQP_S);
        wq0 = pw[((head * 4 + nt) * 2 + 0) * 64 + lane];
        wq1 = pw[((head * 4 + nt) * 2 + 1) * 64 + lane];
        wv0 = pv[((head * 4 + nt) * 2 + 0) * 64 + lane];
        wv1 = pv[((head * 4 + nt) * 2 + 1) * 64 + lane];
      } else {
        int o = head * 64 + nt * 16 + l15;
        wq0 = gath(Wq + o * 64 + g * 8);
        wq1 = gath(Wq + o * 64 + 32 + g * 8);
        wv0 = gath(Wv + o * 128 + 64 + g * 8);
        wv1 = gath(Wv + o * 128 + 64 + 32 + g * 8);
      }
      float4 bv4 = ((const float4*)(bv + head * 64))[nt * 4 + g];
      f32x4 b = (f32x4){bv4.x, bv4.y, bv4.z, bv4.w};
      b = __builtin_amdgcn_mfma_f32_16x16x32_bf16(wv0, qf0, b, 0, 0, 0);
      b = __builtin_amdgcn_mfma_f32_16x16x32_bf16(wv1, qf1, b, 0, 0, 0);
      if (l15 == 0) qv_lds[head][nt][g] = make_float4(b[0], b[1], b[2], b[3]);
    }
    // keep qq in registers (needed as C-in every mt of Phase C)
    #pragma unroll
    for (int nt = 0; nt < 4; ++nt) {
      // note: separate loop so wv-frags above are dead before wq-frags peak again
      ;
    }
  }

  f32x4 qq[4];
  {
    bf16x8 qf0 = gath(q_x + bt * 64 + g * 8);
    bf16x8 qf1 = gath(q_x + bt * 64 + 32 + g * 8);
    #pragma unroll
    for (int nt = 0; nt < 4; ++nt) {
      bf16x8 wq0, wq1;
      if (PREP) {
        const bf16x8* pw = (const bf16x8*)(pack + WQP_S);
        wq0 = pw[((head * 4 + nt) * 2 + 0) * 64 + lane];
        wq1 = pw[((head * 4 + nt) * 2 + 1) * 64 + lane];
      } else {
        int o = head * 64 + nt * 16 + l15;
        wq0 = gath(Wq + o * 64 + g * 8);
        wq1 = gath(Wq + o * 64 + 32 + g * 8);
      }
      float4 bs4 = ((const float4*)bias)[nt * 4 + g];
      f32x4 a = (f32x4){bs4.x, bs4.y, bs4.z, bs4.w};
      a = __builtin_amdgcn_mfma_f32_16x16x32_bf16(wq0, qf0, a, 0, 0, 0);
      a = __builtin_amdgcn_mfma_f32_16x16x32_bf16(wq1, qf1, a, 0, 0, 0);
      qq[nt] = a;
    }
  }

  // ---- per-lane o-vector of score weights + Wk fragments ----
  f32x4 ws4[4];
  bf16x8 bk[4][2];
  #pragma unroll
  for (int nt = 0; nt < 4; ++nt) {
    float4 t = ((const float4*)wsc)[nt * 4 + g];
    ws4[nt] = (f32x4){t.x, t.y, t.z, t.w};
    if (PREP) {
      const bf16x8* pw = (const bf16x8*)(pack + WKP_S);
      bk[nt][0] = pw[((head * 4 + nt) * 2 + 0) * 64 + lane];
      bk[nt][1] = pw[((head * 4 + nt) * 2 + 1) * 64 + lane];
    } else {
      int o = head * 64 + nt * 16 + l15;
      bk[nt][0] = gath(Wk + o * 64 + g * 8);
      bk[nt][1] = gath(Wk + o * 64 + 32 + g * 8);
    }
  }

  __syncthreads();

  // ---- Phase C: keys^T GEMM + tanh-score; score[n=mt*16+l15] in register sr[mt] ----
  float sr[8];
  #pragma unroll
  for (int mt = 0; mt < 8; ++mt) {
    int row = mt * 16 + l15;
    int byte0 = (row << 7) + g * 16;
    int swz = (l15 & 7) << 4;
    bf16x8 a0 = *(const bf16x8*)(&Atile[byte0 ^ swz]);
    bf16x8 a1 = *(const bf16x8*)(&Atile[(byte0 + 64) ^ swz]);
    float p = 0.f;
    #pragma unroll
    for (int nt = 0; nt < 4; ++nt) {
      f32x4 acc = qq[nt];    // C-in = queries + bias (broadcast over cols)
      acc = __builtin_amdgcn_mfma_f32_16x16x32_bf16(bk[nt][0], a0, acc, 0, 0, 0);
      acc = __builtin_amdgcn_mfma_f32_16x16x32_bf16(bk[nt][1], a1, acc, 0, 0, 0);
      #pragma unroll
      for (int r = 0; r < 4; ++r) {
        float e = __expf(2.f * acc[r]);                 // tanh(x) = 1 - 2/(e^(2x)+1)
        float th = 1.f - 2.f * __builtin_amdgcn_rcpf(e + 1.f);
        p = fmaf(ws4[nt][r], th, p);
      }
    }
    p += __shfl_xor(p, 16);    // reduce over o across g-groups
    p += __shfl_xor(p, 32);
    sr[mt] = p;                // full score, identical in all g
  }

  // ---- Phase D: softmax over n=127 (regs + 8 shfl total) ----
  if (l15 == 15) sr[7] = -3.0e38f;        // mask pad row n=127
  float m = fmaxf(fmaxf(fmaxf(sr[0], sr[1]), fmaxf(sr[2], sr[3])),
                  fmaxf(fmaxf(sr[4], sr[5]), fmaxf(sr[6], sr[7])));
  #pragma unroll
  for (int d = 1; d < 16; d <<= 1) m = fmaxf(m, __shfl_xor(m, d));
  float sum = 0.f;
  #pragma unroll
  for (int mt = 0; mt < 8; ++mt) { sr[mt] = __expf(sr[mt] - m); sum += sr[mt]; }
  #pragma unroll
  for (int d = 1; d < 16; d <<= 1) sum += __shfl_xor(sum, d);
  float inv = __builtin_amdgcn_rcpf(sum);
  #pragma unroll
  for (int mt = 0; mt < 8; ++mt) sr[mt] *= inv;   // softmax weight for n=mt*16+l15

  // ---- Phase E: V^T GEMM + weighted accumulate (weights lane-local, zero shfl) ----
  // bw loaded only now: bk is dead, so bk/bw never coexist.
  bf16x8 bw[4][2];
  if (PREP) {
    const bf16x8* pw = (const bf16x8*)(pack + WVP_S);
    #pragma unroll
    for (int nt = 0; nt < 4; ++nt) {
      bw[nt][0] = pw[((head * 4 + nt) * 2 + 0) * 64 + lane];
      bw[nt][1] = pw[((head * 4 + nt) * 2 + 1) * 64 + lane];
    }
  } else {
    #pragma unroll
    for (int nt = 0; nt < 4; ++nt) {
      int o = head * 64 + nt * 16 + l15;
      bw[nt][0] = gath(Wv + o * 128 + g * 8);
      bw[nt][1] = gath(Wv + o * 128 + 32 + g * 8);
    }
  }

  f32x4 cs[4];
  #pragma unroll
  for (int nt = 0; nt < 4; ++nt) cs[nt] = (f32x4){0.f, 0.f, 0.f, 0.f};
  #pragma unroll
  for (int mt = 0; mt < 8; ++mt) {
    int row = mt * 16 + l15;
    int byte0 = (row << 7) + g * 16;
    int swz = (l15 & 7) << 4;
    bf16x8 a0 = *(const bf16x8*)(&Atile[byte0 ^ swz]);
    bf16x8 a1 = *(const bf16x8*)(&Atile[(byte0 + 64) ^ swz]);
    float wgt = sr[mt];
    #pragma unroll
    for (int nt = 0; nt < 4; ++nt) {
      f32x4 vac = (f32x4){0.f, 0.f, 0.f, 0.f};
      vac = __builtin_amdgcn_mfma_f32_16x16x32_bf16(bw[nt][0], a0, vac, 0, 0, 0);
      vac = __builtin_amdgcn_mfma_f32_16x16x32_bf16(bw[nt][1], a1, vac, 0, 0, 0);
      #pragma unroll
      for (int r = 0; r < 4; ++r) cs[nt][r] = fmaf(vac[r], wgt, cs[nt][r]);
    }
  }

  // ---- final reduce over l15, add stashed qv, store ----
  #pragma unroll
  for (int nt = 0; nt < 4; ++nt) {
    #pragma unroll
    for (int d = 1; d < 16; d <<= 1) {
      #pragma unroll
      for (int r = 0; r < 4; ++r) cs[nt][r] += __shfl_xor(cs[nt][r], d);
    }
  }
  if (l15 == 0) {
    #pragma unroll
    for (int nt = 0; nt < 4; ++nt) {
      float4 qv4 = qv_lds[head][nt][g];
      float4 o4 = make_float4(cs[nt][0] + qv4.x, cs[nt][1] + qv4.y,
                              cs[nt][2] + qv4.z, cs[nt][3] + qv4.w);
      ((float4*)out)[bt * 64 + head * 16 + nt * 4 + g] = o4;
    }
  }
}

extern "C" void kernel_launch(void* const* d_in, const int* in_sizes, int n_in,
                              void* d_out, int out_size, void* d_ws, size_t ws_size,
                              hipStream_t stream) {
  const float* q_x  = (const float*)d_in[0];
  const float* kv_x = (const float*)d_in[1];
  const float* Wk   = (const float*)d_in[2];
  const float* Wq   = (const float*)d_in[3];
  const float* Wv   = (const float*)d_in[4];
  const float* bv   = (const float*)d_in[5];
  const float* bias = (const float*)d_in[6];
  const float* wsc  = (const float*)d_in[7];
  // d_in[8] = bs: constant across neighbors -> cancels in softmax, unused.
  float* out = (float*)d_out;
  short* pack = (short*)d_ws;

  if (ws_size >= WS_NEEDED) {
    pack_kernel<<<32, 256, 0, stream>>>(Wk, Wq, Wv, pack);
    rnn_attn_kernel<1><<<1024, 256, 0, stream>>>(q_x, kv_x, Wk, Wq, Wv, bv, bias, wsc, pack, out);
  } else {
    rnn_attn_kernel<0><<<1024, 256, 0, stream>>>(q_x, kv_x, Wk, Wq, Wv, bv, bias, wsc, pack, out);
  }
}

// Round 6
// 31.338 us; speedup vs baseline: 1.7321x; 1.6007x over previous
//
#include <hip/hip_runtime.h>
#include <hip/hip_bf16.h>

// Problem constants: B=8, T=128, n=127 neighbors, Q=K=64, H=4, O=H*K=256
#define NB 127

typedef __attribute__((ext_vector_type(8))) short bf16x8;
typedef __attribute__((ext_vector_type(4))) float f32x4;

// ws layout: packed bf16 MFMA fragments (A/B-frag lane layout is identical), 4 x 32KB.
// short-offsets:
#define WKP_S  0
#define WVP_S  16384
#define WQP_S  32768
#define WVQP_S 49152
#define WS_NEEDED ((size_t)(4 * 16384 * 2))

__device__ __forceinline__ short bfs(float f) {
  __hip_bfloat16 h = __float2bfloat16(f);
  return __builtin_bit_cast(short, h);
}
__device__ __forceinline__ unsigned packbf2(float a, float b) {
  unsigned lo = (unsigned short)bfs(a);
  unsigned hi = (unsigned short)bfs(b);
  return lo | (hi << 16);
}
// gather 8 consecutive floats -> bf16x8 fragment
__device__ __forceinline__ bf16x8 gath(const float* __restrict__ p) {
  float4 a = *(const float4*)p;
  float4 b = *(const float4*)(p + 4);
  bf16x8 f;
  f[0] = bfs(a.x); f[1] = bfs(a.y); f[2] = bfs(a.z); f[3] = bfs(a.w);
  f[4] = bfs(b.x); f[5] = bfs(b.y); f[6] = bfs(b.z); f[7] = bfs(b.w);
  return f;
}

// ================= pack kernel (grid 32): coalesced f32 reads -> fragment-order bf16 ====
// frag layout: lane (= g*16 + l15) of fragment (head,nt,kt) holds
//   W[o = head*64 + nt*16 + l15][k = g*8 + kt*32 + j], j=0..7
__global__ __launch_bounds__(256, 2) void
pack_kernel(const float* __restrict__ Wk, const float* __restrict__ Wq,
            const float* __restrict__ Wv, short* __restrict__ dstall)
{
  const int blk = blockIdx.x;
  const int tid = threadIdx.x;
  const int m = blk >> 3, sub = blk & 7;
  const float* src; int stride, off, dsto;
  if (m == 0)      { src = Wk; stride = 64;  off = 0;  dsto = WKP_S; }
  else if (m == 1) { src = Wv; stride = 128; off = 0;  dsto = WVP_S; }   // Wv kv-part
  else if (m == 2) { src = Wq; stride = 64;  off = 0;  dsto = WQP_S; }
  else             { src = Wv; stride = 128; off = 64; dsto = WVQP_S; }  // Wv q-part
  short* dst = dstall + dsto;
  #pragma unroll
  for (int it = 0; it < 2; ++it) {
    int i4 = sub * 512 + it * 256 + tid;    // float4 index in 256x64 submatrix
    int o = i4 >> 4, c4 = i4 & 15;
    float4 v = ((const float4*)(src + o * stride + off))[c4];
    int k0 = c4 * 4;
    int kt = k0 >> 5, gg = (k0 & 31) >> 3, j0 = k0 & 7;
    int head = o >> 6, nt = (o >> 4) & 3, ol = o & 15;
    int di = ((((head * 4 + nt) * 2 + kt) * 64) + gg * 16 + ol) * 8 + j0;
    *(uint2*)(dst + di) = make_uint2(packbf2(v.x, v.y), packbf2(v.z, v.w));
  }
}

// ================= main kernel (grid 1024, wave = head) =================
// Orientation: mfma(W_frag, kv_frag) -> C[o = g*4+r][n = l15].
// Register discipline: __launch_bounds__(256,2) -> 256-reg cap (no spills);
// partial unroll (2) on mt loops bounds hoisted ds_read operand liveness;
// wv-frags die before wq-frags load; bw loaded only after bk is dead.
template <int PREP>
__global__ __launch_bounds__(256, 2) void
rnn_attn_kernel(const float* __restrict__ q_x, const float* __restrict__ kv_x,
                const float* __restrict__ Wk, const float* __restrict__ Wq,
                const float* __restrict__ Wv, const float* __restrict__ bv,
                const float* __restrict__ bias, const float* __restrict__ wsc,
                const short* __restrict__ pack, float* __restrict__ out)
{
  __shared__ __align__(16) unsigned char Atile[128 * 128];
  __shared__ float4 qv_lds[4][4][4];   // [head][nt][g]

  const int tid = threadIdx.x;
  const int bt = blockIdx.x;
  const int lane = tid & 63;
  const int head = tid >> 6;
  const int l15 = lane & 15;
  const int g = lane >> 4;

  // ---- stage kv tile (127x64 f32 -> bf16, XOR-swizzled), coalesced ----
  const float* kv = kv_x + (size_t)bt * (NB * 64);
  #pragma unroll
  for (int i = 0; i < 8; ++i) {
    int idx = i * 256 + tid;
    int row = idx >> 4, c = idx & 15;
    float4 v = (row < NB) ? ((const float4*)kv)[idx] : make_float4(0.f, 0.f, 0.f, 0.f);
    int byte = (row << 7) + (c << 3);
    byte ^= ((row & 7) << 4);
    *(uint2*)(&Atile[byte]) = make_uint2(packbf2(v.x, v.y), packbf2(v.z, v.w));
  }

  // ---- prologue: qq/qv via broadcast-B MFMA; bias/bv folded in as C-in ----
  // qq[nt][r] = q@Wq.T[o] + bias[o&63], o = head*64+nt*16+g*4+r (same in all l15)
  f32x4 qq[4];
  {
    bf16x8 qf0 = gath(q_x + bt * 64 + g * 8);
    bf16x8 qf1 = gath(q_x + bt * 64 + 32 + g * 8);
    // qv first: wv-frags die before wq-frags are loaded
    #pragma unroll
    for (int nt = 0; nt < 4; ++nt) {
      bf16x8 wv0, wv1;
      if (PREP) {
        const bf16x8* pv = (const bf16x8*)(pack + WVQP_S);
        wv0 = pv[((head * 4 + nt) * 2 + 0) * 64 + lane];
        wv1 = pv[((head * 4 + nt) * 2 + 1) * 64 + lane];
      } else {
        int o = head * 64 + nt * 16 + l15;
        wv0 = gath(Wv + o * 128 + 64 + g * 8);
        wv1 = gath(Wv + o * 128 + 64 + 32 + g * 8);
      }
      float4 bv4 = ((const float4*)(bv + head * 64))[nt * 4 + g];
      f32x4 b = (f32x4){bv4.x, bv4.y, bv4.z, bv4.w};
      b = __builtin_amdgcn_mfma_f32_16x16x32_bf16(wv0, qf0, b, 0, 0, 0);
      b = __builtin_amdgcn_mfma_f32_16x16x32_bf16(wv1, qf1, b, 0, 0, 0);
      if (l15 == 0) qv_lds[head][nt][g] = make_float4(b[0], b[1], b[2], b[3]);
    }
    #pragma unroll
    for (int nt = 0; nt < 4; ++nt) {
      bf16x8 wq0, wq1;
      if (PREP) {
        const bf16x8* pw = (const bf16x8*)(pack + WQP_S);
        wq0 = pw[((head * 4 + nt) * 2 + 0) * 64 + lane];
        wq1 = pw[((head * 4 + nt) * 2 + 1) * 64 + lane];
      } else {
        int o = head * 64 + nt * 16 + l15;
        wq0 = gath(Wq + o * 64 + g * 8);
        wq1 = gath(Wq + o * 64 + 32 + g * 8);
      }
      float4 bs4 = ((const float4*)bias)[nt * 4 + g];
      f32x4 a = (f32x4){bs4.x, bs4.y, bs4.z, bs4.w};
      a = __builtin_amdgcn_mfma_f32_16x16x32_bf16(wq0, qf0, a, 0, 0, 0);
      a = __builtin_amdgcn_mfma_f32_16x16x32_bf16(wq1, qf1, a, 0, 0, 0);
      qq[nt] = a;
    }
  }

  // ---- per-lane o-vector of score weights + Wk fragments ----
  f32x4 ws4[4];
  bf16x8 bk[4][2];
  #pragma unroll
  for (int nt = 0; nt < 4; ++nt) {
    float4 t = ((const float4*)wsc)[nt * 4 + g];
    ws4[nt] = (f32x4){t.x, t.y, t.z, t.w};
    if (PREP) {
      const bf16x8* pw = (const bf16x8*)(pack + WKP_S);
      bk[nt][0] = pw[((head * 4 + nt) * 2 + 0) * 64 + lane];
      bk[nt][1] = pw[((head * 4 + nt) * 2 + 1) * 64 + lane];
    } else {
      int o = head * 64 + nt * 16 + l15;
      bk[nt][0] = gath(Wk + o * 64 + g * 8);
      bk[nt][1] = gath(Wk + o * 64 + 32 + g * 8);
    }
  }

  __syncthreads();

  // ---- Phase C: keys^T GEMM + tanh-score; score[n=mt*16+l15] in register sr[mt] ----
  float sr[8];
  #pragma unroll 2
  for (int mt = 0; mt < 8; ++mt) {
    int row = mt * 16 + l15;
    int byte0 = (row << 7) + g * 16;
    int swz = (l15 & 7) << 4;
    bf16x8 a0 = *(const bf16x8*)(&Atile[byte0 ^ swz]);
    bf16x8 a1 = *(const bf16x8*)(&Atile[(byte0 + 64) ^ swz]);
    float p = 0.f;
    #pragma unroll
    for (int nt = 0; nt < 4; ++nt) {
      f32x4 acc = qq[nt];    // C-in = queries + bias (broadcast over cols)
      acc = __builtin_amdgcn_mfma_f32_16x16x32_bf16(bk[nt][0], a0, acc, 0, 0, 0);
      acc = __builtin_amdgcn_mfma_f32_16x16x32_bf16(bk[nt][1], a1, acc, 0, 0, 0);
      #pragma unroll
      for (int r = 0; r < 4; ++r) {
        float e = __expf(2.f * acc[r]);                 // tanh(x) = 1 - 2/(e^(2x)+1)
        float th = 1.f - 2.f * __builtin_amdgcn_rcpf(e + 1.f);
        p = fmaf(ws4[nt][r], th, p);
      }
    }
    p += __shfl_xor(p, 16);    // reduce over o across g-groups
    p += __shfl_xor(p, 32);
    sr[mt] = p;                // full score, identical in all g
  }

  // ---- Phase D: softmax over n=127 (regs + 8 shfl total) ----
  if (l15 == 15) sr[7] = -3.0e38f;        // mask pad row n=127
  float m = fmaxf(fmaxf(fmaxf(sr[0], sr[1]), fmaxf(sr[2], sr[3])),
                  fmaxf(fmaxf(sr[4], sr[5]), fmaxf(sr[6], sr[7])));
  #pragma unroll
  for (int d = 1; d < 16; d <<= 1) m = fmaxf(m, __shfl_xor(m, d));
  float sum = 0.f;
  #pragma unroll
  for (int mt = 0; mt < 8; ++mt) { sr[mt] = __expf(sr[mt] - m); sum += sr[mt]; }
  #pragma unroll
  for (int d = 1; d < 16; d <<= 1) sum += __shfl_xor(sum, d);
  float inv = __builtin_amdgcn_rcpf(sum);
  #pragma unroll
  for (int mt = 0; mt < 8; ++mt) sr[mt] *= inv;   // softmax weight for n=mt*16+l15

  // ---- Phase E: V^T GEMM + weighted accumulate (weights lane-local, zero shfl) ----
  // bw loaded only now: bk is dead, so bk/bw never coexist.
  bf16x8 bw[4][2];
  if (PREP) {
    const bf16x8* pw = (const bf16x8*)(pack + WVP_S);
    #pragma unroll
    for (int nt = 0; nt < 4; ++nt) {
      bw[nt][0] = pw[((head * 4 + nt) * 2 + 0) * 64 + lane];
      bw[nt][1] = pw[((head * 4 + nt) * 2 + 1) * 64 + lane];
    }
  } else {
    #pragma unroll
    for (int nt = 0; nt < 4; ++nt) {
      int o = head * 64 + nt * 16 + l15;
      bw[nt][0] = gath(Wv + o * 128 + g * 8);
      bw[nt][1] = gath(Wv + o * 128 + 32 + g * 8);
    }
  }

  f32x4 cs[4];
  #pragma unroll
  for (int nt = 0; nt < 4; ++nt) cs[nt] = (f32x4){0.f, 0.f, 0.f, 0.f};
  #pragma unroll 2
  for (int mt = 0; mt < 8; ++mt) {
    int row = mt * 16 + l15;
    int byte0 = (row << 7) + g * 16;
    int swz = (l15 & 7) << 4;
    bf16x8 a0 = *(const bf16x8*)(&Atile[byte0 ^ swz]);
    bf16x8 a1 = *(const bf16x8*)(&Atile[(byte0 + 64) ^ swz]);
    float wgt = sr[mt];
    #pragma unroll
    for (int nt = 0; nt < 4; ++nt) {
      f32x4 vac = (f32x4){0.f, 0.f, 0.f, 0.f};
      vac = __builtin_amdgcn_mfma_f32_16x16x32_bf16(bw[nt][0], a0, vac, 0, 0, 0);
      vac = __builtin_amdgcn_mfma_f32_16x16x32_bf16(bw[nt][1], a1, vac, 0, 0, 0);
      #pragma unroll
      for (int r = 0; r < 4; ++r) cs[nt][r] = fmaf(vac[r], wgt, cs[nt][r]);
    }
  }

  // ---- final reduce over l15, add stashed qv, store ----
  #pragma unroll
  for (int nt = 0; nt < 4; ++nt) {
    #pragma unroll
    for (int d = 1; d < 16; d <<= 1) {
      #pragma unroll
      for (int r = 0; r < 4; ++r) cs[nt][r] += __shfl_xor(cs[nt][r], d);
    }
  }
  if (l15 == 0) {
    #pragma unroll
    for (int nt = 0; nt < 4; ++nt) {
      float4 qv4 = qv_lds[head][nt][g];
      float4 o4 = make_float4(cs[nt][0] + qv4.x, cs[nt][1] + qv4.y,
                              cs[nt][2] + qv4.z, cs[nt][3] + qv4.w);
      ((float4*)out)[bt * 64 + head * 16 + nt * 4 + g] = o4;
    }
  }
}

extern "C" void kernel_launch(void* const* d_in, const int* in_sizes, int n_in,
                              void* d_out, int out_size, void* d_ws, size_t ws_size,
                              hipStream_t stream) {
  const float* q_x  = (const float*)d_in[0];
  const float* kv_x = (const float*)d_in[1];
  const float* Wk   = (const float*)d_in[2];
  const float* Wq   = (const float*)d_in[3];
  const float* Wv   = (const float*)d_in[4];
  const float* bv   = (const float*)d_in[5];
  const float* bias = (const float*)d_in[6];
  const float* wsc  = (const float*)d_in[7];
  // d_in[8] = bs: constant across neighbors -> cancels in softmax, unused.
  float* out = (float*)d_out;
  short* pack = (short*)d_ws;

  if (ws_size >= WS_NEEDED) {
    pack_kernel<<<32, 256, 0, stream>>>(Wk, Wq, Wv, pack);
    rnn_attn_kernel<1><<<1024, 256, 0, stream>>>(q_x, kv_x, Wk, Wq, Wv, bv, bias, wsc, pack, out);
  } else {
    rnn_attn_kernel<0><<<1024, 256, 0, stream>>>(q_x, kv_x, Wk, Wq, Wv, bv, bias, wsc, pack, out);
  }
}